// Round 4
// baseline (5613.242 us; speedup 1.0000x reference)
//
#include <hip/hip_runtime.h>
#include <hip/hip_bf16.h>
#include <cmath>

#define DIM 2048
#define NHEADS 16
#define HDIM 128
#define SEQ 2048
#define BATCH 2
#define MTOT (BATCH*SEQ)
#define RMS_EPS 1.1920928955078125e-07f

// ---------------------------------------------------------------------------
// GEMM (NT): C[M,N] = A[M,K] @ B[N,K]^T, all row-major fp32.
// 128x128 tile, BK=16, 256 threads, 8x8 microtile per thread.
// Selects among 3 (B,C) pairs via blockIdx.z so QKV is one launch.
// (Measured R3: ~93 TF combined = 59% of fp32 vector peak. MFMA next round.)
// ---------------------------------------------------------------------------
__global__ __launch_bounds__(256) void gemm_nt_f32(
    const float* __restrict__ A,
    const float* __restrict__ B0, const float* __restrict__ B1, const float* __restrict__ B2,
    float* __restrict__ C0, float* __restrict__ C1, float* __restrict__ C2,
    int M, int N, int K)
{
    const float* B = (blockIdx.z == 0) ? B0 : (blockIdx.z == 1 ? B1 : B2);
    float*       C = (blockIdx.z == 0) ? C0 : (blockIdx.z == 1 ? C1 : C2);

    __shared__ float As[16][132];   // [k][m], pad 132 to de-conflict stores
    __shared__ float Bs[16][132];   // [k][n]

    const int tid = threadIdx.x;
    const int m0 = blockIdx.y * 128;
    const int n0 = blockIdx.x * 128;
    const int lr = tid >> 2;          // 0..63 (loader row)
    const int lc = (tid & 3) << 2;    // 0,4,8,12 (loader k-col)
    const int ty = tid >> 4;          // 0..15
    const int tx = tid & 15;          // 0..15

    float acc[8][8] = {};

    for (int k0 = 0; k0 < K; k0 += 16) {
        float4 a0 = *(const float4*)&A[(size_t)(m0 + lr)      * K + k0 + lc];
        float4 a1 = *(const float4*)&A[(size_t)(m0 + lr + 64) * K + k0 + lc];
        float4 b0 = *(const float4*)&B[(size_t)(n0 + lr)      * K + k0 + lc];
        float4 b1 = *(const float4*)&B[(size_t)(n0 + lr + 64) * K + k0 + lc];
        __syncthreads();   // previous iteration's fragment reads complete
        As[lc+0][lr]    = a0.x; As[lc+1][lr]    = a0.y; As[lc+2][lr]    = a0.z; As[lc+3][lr]    = a0.w;
        As[lc+0][lr+64] = a1.x; As[lc+1][lr+64] = a1.y; As[lc+2][lr+64] = a1.z; As[lc+3][lr+64] = a1.w;
        Bs[lc+0][lr]    = b0.x; Bs[lc+1][lr]    = b0.y; Bs[lc+2][lr]    = b0.z; Bs[lc+3][lr]    = b0.w;
        Bs[lc+0][lr+64] = b1.x; Bs[lc+1][lr+64] = b1.y; Bs[lc+2][lr+64] = b1.z; Bs[lc+3][lr+64] = b1.w;
        __syncthreads();
        #pragma unroll
        for (int kk = 0; kk < 16; ++kk) {
            float a[8], b[8];
            *(float4*)&a[0] = *(const float4*)&As[kk][ty*8];
            *(float4*)&a[4] = *(const float4*)&As[kk][ty*8+4];
            *(float4*)&b[0] = *(const float4*)&Bs[kk][tx*8];
            *(float4*)&b[4] = *(const float4*)&Bs[kk][tx*8+4];
            #pragma unroll
            for (int i = 0; i < 8; ++i)
                #pragma unroll
                for (int j = 0; j < 8; ++j)
                    acc[i][j] = fmaf(a[i], b[j], acc[i][j]);
        }
    }
    #pragma unroll
    for (int i = 0; i < 8; ++i) {
        size_t row = (size_t)(m0 + ty*8 + i);
        float4 o0 = make_float4(acc[i][0], acc[i][1], acc[i][2], acc[i][3]);
        float4 o1 = make_float4(acc[i][4], acc[i][5], acc[i][6], acc[i][7]);
        *(float4*)&C[row * N + n0 + tx*8]     = o0;
        *(float4*)&C[row * N + n0 + tx*8 + 4] = o1;
    }
}

// ---------------------------------------------------------------------------
// Fused RMSNorm (per head, over 128) + RoPE (half-split rotary).
// One wave per (row m, head h). Lane j owns the pair (d=j, d=j+64).
// grid: (MTOT/4, NHEADS, 2[Q,K]); block: 256 = 4 waves.
// ---------------------------------------------------------------------------
__global__ __launch_bounds__(256) void rmsnorm_rope(float* __restrict__ Q,
                                                    float* __restrict__ Kp)
{
    const int wave = threadIdx.x >> 6;
    const int lane = threadIdx.x & 63;
    const int m = blockIdx.x * 4 + wave;          // 0..4095
    const int h = blockIdx.y;
    float* T = blockIdx.z ? Kp : Q;
    const int s = m & (SEQ - 1);                  // position within sequence

    float* row = T + (size_t)m * DIM + h * HDIM;
    float x1 = row[lane];
    float x2 = row[lane + 64];

    float ss = x1*x1 + x2*x2;
    #pragma unroll
    for (int off = 32; off > 0; off >>= 1) ss += __shfl_xor(ss, off);
    const float r = rsqrtf(ss * (1.0f/128.0f) + RMS_EPS);
    x1 *= r; x2 *= r;

    // inv_freq = 1 / base^(2j/128), j = lane
    const float e = (float)lane * (1.0f/64.0f);
    const float inv_freq = 1.0f / powf(10000.0f, e);
    const float fr = (float)s * inv_freq;
    const float c = cosf(fr), sn = sinf(fr);

    row[lane]      =  x1 * c + x2 * sn;
    row[lane + 64] = -x1 * sn + x2 * c;
}

// ---------------------------------------------------------------------------
// Flash-style causal attention, fp32, balanced + conflict-free rewrite.
//  - Block handles q-tile PAIR (q, 31-q) sequentially -> uniform 68 k-tiles.
//    grid (16, NHEADS, BATCH) = 512 blocks = exactly 2/CU, one balanced round.
//  - 512 threads (8 waves); LDS 74.5 KB -> 2 blocks/CU = 16 waves/CU.
//  - ty = tid>>4 (0..31): rows {2ty, 2ty+1}; tx = tid&15: score cols
//    {2tx, 2tx+1}, PV d-chunks {4tx..4tx+3, 64+4tx..}.
//  - Qs/Ks XOR-swizzled by (row>>1)&7 in 16B quads:
//      score Q-read: 4 rows/wave -> 4 distinct quads (conflict-free)
//      score K-read: reordered loop j = kd4^swk -> K linear (imm offsets),
//                    16 rows over 8 quads = 2-way (free per m136)
//  - Vs linear, PV reads at 16B lane stride -> 2-way (free).
//  - Ps stride 35 floats -> PV broadcast reads conflict-free.
// ---------------------------------------------------------------------------
__global__ __launch_bounds__(512, 4) void attn_f32(
    const float* __restrict__ Q, const float* __restrict__ Kp,
    const float* __restrict__ V, float* __restrict__ Y)
{
    const int qpair = blockIdx.x;          // 0..15
    const int h = blockIdx.y, b = blockIdx.z;
    const int tid = threadIdx.x;
    const int ty = tid >> 4;               // 0..31
    const int tx = tid & 15;               // 0..15

    __shared__ float Qs[64][HDIM];         // swizzled, 32 KB
    __shared__ float Ks[32][HDIM];         // swizzled, 16 KB
    __shared__ float Vs[32][HDIM];         // linear,   16 KB
    __shared__ float Ps[64][35];           // stride 35, 8.75 KB

    const size_t headoff = (size_t)h * HDIM;
    const float* Kbase = Kp + ((size_t)(b*SEQ)) * DIM + headoff;
    const float* Vbase = V  + ((size_t)(b*SEQ)) * DIM + headoff;
    const float scale = 0.08838834764831845f;  // 1/sqrt(128)

    const int swk = tx & 7;                // ((2tx+j)>>1)&7, j=0,1
    const int swq = ty & 7;                // ((2ty+i)>>1)&7, i=0,1
    const int sqk = swk ^ swq;
    const int d0  = tx * 4;

    for (int phase = 0; phase < 2; ++phase) {
        const int qt = phase ? (SEQ/64 - 1 - qpair) : qpair;
        const float* Qbase = Q + ((size_t)(b*SEQ + qt*64)) * DIM + headoff;

        // stage Q tile (scaled, swizzled): 2048 float4 / 512 thr = 4 each.
        // Safe vs other waves: they are at/past last tile's PV (reads Vs/Ps
        // only); the kt-loop's first barrier orders these writes before reads.
        #pragma unroll
        for (int i = 0; i < 4; ++i) {
            int f = tid + i*512;
            int row = f >> 5, c4 = f & 31;
            float4 qv = *(const float4*)&Qbase[(size_t)row * DIM + (c4 << 2)];
            qv.x *= scale; qv.y *= scale; qv.z *= scale; qv.w *= scale;
            int c4s = c4 ^ ((row >> 1) & 7);
            *(float4*)&Qs[row][c4s << 2] = qv;
        }

        float m_i[2] = {-INFINITY, -INFINITY};
        float l_i[2] = {0.0f, 0.0f};
        float O[2][8] = {};

        const int ntiles = 2*qt + 2;
        for (int kt = 0; kt < ntiles; ++kt) {
            // prefetch K/V tile to regs: 1024 float4 each / 512 thr = 2 each
            float4 kreg[2], vreg[2];
            int rrow[2], rc4[2];
            #pragma unroll
            for (int i = 0; i < 2; ++i) {
                int f = tid + i*512;
                rrow[i] = f >> 5; rc4[i] = f & 31;
                size_t g = (size_t)(kt*32 + rrow[i]) * DIM + (rc4[i] << 2);
                kreg[i] = *(const float4*)&Kbase[g];
                vreg[i] = *(const float4*)&Vbase[g];
            }
            __syncthreads();   // prior tile's PV reads of Vs/Ps done; Qs staged
            #pragma unroll
            for (int i = 0; i < 2; ++i) {
                int c4s = rc4[i] ^ ((rrow[i] >> 1) & 7);
                *(float4*)&Ks[rrow[i]][c4s << 2] = kreg[i];
                *(float4*)&Vs[rrow[i]][rc4[i] << 2] = vreg[i];
            }
            __syncthreads();

            // ---- scores: rows {2ty+i}, cols {2tx+j}; loop j = kd4^swk so
            //      K reads are linear (immediate offsets) ----
            float s00 = 0.f, s01 = 0.f, s10 = 0.f, s11 = 0.f;
            const int r0 = tx*2, r1 = r0 + 1;
            #pragma unroll
            for (int j = 0; j < 32; ++j) {
                float4 k0 = *(const float4*)&Ks[r0][j << 2];
                float4 k1 = *(const float4*)&Ks[r1][j << 2];
                const int jq = (j ^ sqk) << 2;
                float4 q0 = *(const float4*)&Qs[ty*2][jq];
                float4 q1 = *(const float4*)&Qs[ty*2 + 1][jq];
                s00 = fmaf(q0.x,k0.x,s00); s00 = fmaf(q0.y,k0.y,s00);
                s00 = fmaf(q0.z,k0.z,s00); s00 = fmaf(q0.w,k0.w,s00);
                s01 = fmaf(q0.x,k1.x,s01); s01 = fmaf(q0.y,k1.y,s01);
                s01 = fmaf(q0.z,k1.z,s01); s01 = fmaf(q0.w,k1.w,s01);
                s10 = fmaf(q1.x,k0.x,s10); s10 = fmaf(q1.y,k0.y,s10);
                s10 = fmaf(q1.z,k0.z,s10); s10 = fmaf(q1.w,k0.w,s10);
                s11 = fmaf(q1.x,k1.x,s11); s11 = fmaf(q1.y,k1.y,s11);
                s11 = fmaf(q1.z,k1.z,s11); s11 = fmaf(q1.w,k1.w,s11);
            }
            float sc[2][2] = {{s00, s01}, {s10, s11}};

            // ---- online softmax (row spread over 16 tx lanes) ----
            const int qg0 = qt*64 + ty*2;
            const int kg0 = kt*32 + tx*2;
            #pragma unroll
            for (int i = 0; i < 2; ++i) {
                const int qg = qg0 + i;
                if (kg0     > qg) sc[i][0] = -INFINITY;
                if (kg0 + 1 > qg) sc[i][1] = -INFINITY;
                float mx = fmaxf(sc[i][0], sc[i][1]);
                #pragma unroll
                for (int off = 1; off < 16; off <<= 1) mx = fmaxf(mx, __shfl_xor(mx, off));
                const float mnew = fmaxf(m_i[i], mx);
                const float alpha = __expf(m_i[i] - mnew);   // 0 on first tile
                const float p0 = __expf(sc[i][0] - mnew);
                const float p1 = __expf(sc[i][1] - mnew);
                float rs = p0 + p1;
                #pragma unroll
                for (int off = 1; off < 16; off <<= 1) rs += __shfl_xor(rs, off);
                l_i[i] = l_i[i]*alpha + rs;
                m_i[i] = mnew;
                #pragma unroll
                for (int d = 0; d < 8; ++d) O[i][d] *= alpha;
                *(float2*)&Ps[ty*2 + i][tx*2] = make_float2(p0, p1);
            }
            __syncthreads();

            // ---- PV: O[i][·] += P[row][kc] * V[kc][{d0, 64+d0}] ----
            #pragma unroll 4
            for (int kc = 0; kc < 32; ++kc) {
                float4 v0 = *(const float4*)&Vs[kc][d0];
                float4 v1 = *(const float4*)&Vs[kc][64 + d0];
                #pragma unroll
                for (int i = 0; i < 2; ++i) {
                    const float p = Ps[ty*2 + i][kc];
                    O[i][0] = fmaf(p, v0.x, O[i][0]);
                    O[i][1] = fmaf(p, v0.y, O[i][1]);
                    O[i][2] = fmaf(p, v0.z, O[i][2]);
                    O[i][3] = fmaf(p, v0.w, O[i][3]);
                    O[i][4] = fmaf(p, v1.x, O[i][4]);
                    O[i][5] = fmaf(p, v1.y, O[i][5]);
                    O[i][6] = fmaf(p, v1.z, O[i][6]);
                    O[i][7] = fmaf(p, v1.w, O[i][7]);
                }
            }
            // next iteration's first __syncthreads orders Vs/Ps overwrite
        }

        // ---- epilogue: normalize, store Y rows of THIS q-tile ----
        // Y aliases Q: this block's phase-qt Q rows were consumed into LDS.
        #pragma unroll
        for (int i = 0; i < 2; ++i) {
            const float inv = 1.0f / l_i[i];
            const size_t row = (size_t)(b*SEQ + qt*64 + ty*2 + i);
            float4 o0 = make_float4(O[i][0]*inv, O[i][1]*inv, O[i][2]*inv, O[i][3]*inv);
            float4 o1 = make_float4(O[i][4]*inv, O[i][5]*inv, O[i][6]*inv, O[i][7]*inv);
            *(float4*)&Y[row * DIM + headoff + d0]      = o0;
            *(float4*)&Y[row * DIM + headoff + 64 + d0] = o1;
        }
    }
}

// ---------------------------------------------------------------------------
extern "C" void kernel_launch(void* const* d_in, const int* in_sizes, int n_in,
                              void* d_out, int out_size, void* d_ws, size_t ws_size,
                              hipStream_t stream)
{
    const float* x  = (const float*)d_in[0];
    const float* Wq = (const float*)d_in[1];
    const float* Wk = (const float*)d_in[2];
    const float* Wv = (const float*)d_in[3];
    const float* Wo = (const float*)d_in[4];
    float* out = (float*)d_out;

    // Workspace: 3 buffers of 32 MB (Q, K, V). Attention output Y aliases Q
    // (each attn block stages its Q rows to LDS before writing the same rows;
    //  cross-block regions are disjoint in (rows x head-cols)).
    float* Qb = (float*)d_ws;
    float* Kb = Qb + (size_t)MTOT * DIM;
    float* Vb = Kb + (size_t)MTOT * DIM;
    float* Yb = Qb;

    // QKV projections (one launch, z selects W/out)
    gemm_nt_f32<<<dim3(DIM/128, MTOT/128, 3), dim3(256), 0, stream>>>(
        x, Wq, Wk, Wv, Qb, Kb, Vb, MTOT, DIM, DIM);
    // fused RMSNorm + RoPE on Q and K
    rmsnorm_rope<<<dim3(MTOT/4, NHEADS, 2), dim3(256), 0, stream>>>(Qb, Kb);
    // causal flash attention, balanced q-tile pairing (Y aliases Q)
    attn_f32<<<dim3(SEQ/128, NHEADS, BATCH), dim3(512), 0, stream>>>(Qb, Kb, Vb, Yb);
    // output projection
    gemm_nt_f32<<<dim3(DIM/128, MTOT/128, 1), dim3(256), 0, stream>>>(
        Yb, Wo, Wo, Wo, out, out, out, MTOT, DIM, DIM);
}

// Round 5
// 2614.450 us; speedup vs baseline: 2.1470x; 2.1470x over previous
//
#include <hip/hip_runtime.h>
#include <hip/hip_bf16.h>
#include <cmath>

#define DIM 2048
#define NHEADS 16
#define HDIM 128
#define SEQ 2048
#define BATCH 2
#define MTOT (BATCH*SEQ)
#define RMS_EPS 1.1920928955078125e-07f

// ---------------------------------------------------------------------------
// GEMM (NT): C[M,N] = A[M,K] @ B[N,K]^T, all row-major fp32.
// 128x128 tile, BK=16, 256 threads, 8x8 microtile per thread.
// (Measured R3: ~93 TF combined = 59% of fp32 vector peak. MFMA next.)
// ---------------------------------------------------------------------------
__global__ __launch_bounds__(256) void gemm_nt_f32(
    const float* __restrict__ A,
    const float* __restrict__ B0, const float* __restrict__ B1, const float* __restrict__ B2,
    float* __restrict__ C0, float* __restrict__ C1, float* __restrict__ C2,
    int M, int N, int K)
{
    const float* B = (blockIdx.z == 0) ? B0 : (blockIdx.z == 1 ? B1 : B2);
    float*       C = (blockIdx.z == 0) ? C0 : (blockIdx.z == 1 ? C1 : C2);

    __shared__ float As[16][132];   // [k][m], pad 132 to de-conflict stores
    __shared__ float Bs[16][132];   // [k][n]

    const int tid = threadIdx.x;
    const int m0 = blockIdx.y * 128;
    const int n0 = blockIdx.x * 128;
    const int lr = tid >> 2;          // 0..63 (loader row)
    const int lc = (tid & 3) << 2;    // 0,4,8,12 (loader k-col)
    const int ty = tid >> 4;          // 0..15
    const int tx = tid & 15;          // 0..15

    float acc[8][8] = {};

    for (int k0 = 0; k0 < K; k0 += 16) {
        float4 a0 = *(const float4*)&A[(size_t)(m0 + lr)      * K + k0 + lc];
        float4 a1 = *(const float4*)&A[(size_t)(m0 + lr + 64) * K + k0 + lc];
        float4 b0 = *(const float4*)&B[(size_t)(n0 + lr)      * K + k0 + lc];
        float4 b1 = *(const float4*)&B[(size_t)(n0 + lr + 64) * K + k0 + lc];
        __syncthreads();   // previous iteration's fragment reads complete
        As[lc+0][lr]    = a0.x; As[lc+1][lr]    = a0.y; As[lc+2][lr]    = a0.z; As[lc+3][lr]    = a0.w;
        As[lc+0][lr+64] = a1.x; As[lc+1][lr+64] = a1.y; As[lc+2][lr+64] = a1.z; As[lc+3][lr+64] = a1.w;
        Bs[lc+0][lr]    = b0.x; Bs[lc+1][lr]    = b0.y; Bs[lc+2][lr]    = b0.z; Bs[lc+3][lr]    = b0.w;
        Bs[lc+0][lr+64] = b1.x; Bs[lc+1][lr+64] = b1.y; Bs[lc+2][lr+64] = b1.z; Bs[lc+3][lr+64] = b1.w;
        __syncthreads();
        #pragma unroll
        for (int kk = 0; kk < 16; ++kk) {
            float a[8], b[8];
            *(float4*)&a[0] = *(const float4*)&As[kk][ty*8];
            *(float4*)&a[4] = *(const float4*)&As[kk][ty*8+4];
            *(float4*)&b[0] = *(const float4*)&Bs[kk][tx*8];
            *(float4*)&b[4] = *(const float4*)&Bs[kk][tx*8+4];
            #pragma unroll
            for (int i = 0; i < 8; ++i)
                #pragma unroll
                for (int j = 0; j < 8; ++j)
                    acc[i][j] = fmaf(a[i], b[j], acc[i][j]);
        }
    }
    #pragma unroll
    for (int i = 0; i < 8; ++i) {
        size_t row = (size_t)(m0 + ty*8 + i);
        float4 o0 = make_float4(acc[i][0], acc[i][1], acc[i][2], acc[i][3]);
        float4 o1 = make_float4(acc[i][4], acc[i][5], acc[i][6], acc[i][7]);
        *(float4*)&C[row * N + n0 + tx*8]     = o0;
        *(float4*)&C[row * N + n0 + tx*8 + 4] = o1;
    }
}

// ---------------------------------------------------------------------------
// Fused RMSNorm (per head, over 128) + RoPE (half-split rotary).
// One wave per (row m, head h). Lane j owns the pair (d=j, d=j+64).
// ---------------------------------------------------------------------------
__global__ __launch_bounds__(256) void rmsnorm_rope(float* __restrict__ Q,
                                                    float* __restrict__ Kp)
{
    const int wave = threadIdx.x >> 6;
    const int lane = threadIdx.x & 63;
    const int m = blockIdx.x * 4 + wave;          // 0..4095
    const int h = blockIdx.y;
    float* T = blockIdx.z ? Kp : Q;
    const int s = m & (SEQ - 1);                  // position within sequence

    float* row = T + (size_t)m * DIM + h * HDIM;
    float x1 = row[lane];
    float x2 = row[lane + 64];

    float ss = x1*x1 + x2*x2;
    #pragma unroll
    for (int off = 32; off > 0; off >>= 1) ss += __shfl_xor(ss, off);
    const float r = rsqrtf(ss * (1.0f/128.0f) + RMS_EPS);
    x1 *= r; x2 *= r;

    const float e = (float)lane * (1.0f/64.0f);
    const float inv_freq = 1.0f / powf(10000.0f, e);
    const float fr = (float)s * inv_freq;
    const float c = cosf(fr), sn = sinf(fr);

    row[lane]      =  x1 * c + x2 * sn;
    row[lane + 64] = -x1 * sn + x2 * c;
}

// ---------------------------------------------------------------------------
// Flash-style causal attention, fp32. R4 structure (balanced q-tile pairing,
// 512 threads, 2 blocks/CU) + R5 conflict fix:
//   BOTH Qs and Ks stored XOR-swizzled by (row>>1)&7 in 16B quads, and BOTH
//   read with the per-thread read-side XOR (R4 read K physically-linear ->
//   16-way conflict, 1.79e9 conflict cycles; the XOR must be paid on READ).
// Bank audit (16-lane quarter-groups):
//   K score read: quads (j^ (tx&7))&7 span 8, 2 rows each  -> 2-way (free)
//   Q score read: broadcast within tx group, 4 quads across ty -> free
//   staging stores: 8 quads x2 -> 2-way (free)
//   V PV read at 16B lane stride -> 2-way (free); Ps stride 35 -> free
// ---------------------------------------------------------------------------
__global__ __launch_bounds__(512, 4) void attn_f32(
    const float* __restrict__ Q, const float* __restrict__ Kp,
    const float* __restrict__ V, float* __restrict__ Y)
{
    const int qpair = blockIdx.x;          // 0..15
    const int h = blockIdx.y, b = blockIdx.z;
    const int tid = threadIdx.x;
    const int ty = tid >> 4;               // 0..31
    const int tx = tid & 15;               // 0..15

    __shared__ float Qs[64][HDIM];         // swizzled, 32 KB
    __shared__ float Ks[32][HDIM];         // swizzled, 16 KB
    __shared__ float Vs[32][HDIM];         // linear,   16 KB
    __shared__ float Ps[64][35];           // stride 35, 8.75 KB

    const size_t headoff = (size_t)h * HDIM;
    const float* Kbase = Kp + ((size_t)(b*SEQ)) * DIM + headoff;
    const float* Vbase = V  + ((size_t)(b*SEQ)) * DIM + headoff;
    const float scale = 0.08838834764831845f;  // 1/sqrt(128)

    const int swk = tx & 7;                // ((2tx+jj)>>1)&7, jj=0,1
    const int swq = ty & 7;                // ((2ty+i)>>1)&7,  i=0,1
    const int d0  = tx * 4;

    for (int phase = 0; phase < 2; ++phase) {
        const int qt = phase ? (SEQ/64 - 1 - qpair) : qpair;
        const float* Qbase = Q + ((size_t)(b*SEQ + qt*64)) * DIM + headoff;

        // stage Q tile (scaled, swizzled): 2048 float4 / 512 thr = 4 each.
        // Other waves are in last tile's PV (reads Vs/Ps only); the kt-loop's
        // first barrier orders these writes before any Qs read.
        #pragma unroll
        for (int i = 0; i < 4; ++i) {
            int f = tid + i*512;
            int row = f >> 5, c4 = f & 31;
            float4 qv = *(const float4*)&Qbase[(size_t)row * DIM + (c4 << 2)];
            qv.x *= scale; qv.y *= scale; qv.z *= scale; qv.w *= scale;
            int c4s = c4 ^ ((row >> 1) & 7);
            *(float4*)&Qs[row][c4s << 2] = qv;
        }

        float m_i[2] = {-INFINITY, -INFINITY};
        float l_i[2] = {0.0f, 0.0f};
        float O[2][8] = {};

        const int ntiles = 2*qt + 2;
        for (int kt = 0; kt < ntiles; ++kt) {
            // prefetch K/V tile to regs: 1024 float4 each / 512 thr = 2 each
            float4 kreg[2], vreg[2];
            int rrow[2], rc4[2];
            #pragma unroll
            for (int i = 0; i < 2; ++i) {
                int f = tid + i*512;
                rrow[i] = f >> 5; rc4[i] = f & 31;
                size_t g = (size_t)(kt*32 + rrow[i]) * DIM + (rc4[i] << 2);
                kreg[i] = *(const float4*)&Kbase[g];
                vreg[i] = *(const float4*)&Vbase[g];
            }
            __syncthreads();   // prior tile's PV reads of Vs/Ps done; Qs staged
            #pragma unroll
            for (int i = 0; i < 2; ++i) {
                int c4s = rc4[i] ^ ((rrow[i] >> 1) & 7);
                *(float4*)&Ks[rrow[i]][c4s << 2] = kreg[i];
                *(float4*)&Vs[rrow[i]][rc4[i] << 2] = vreg[i];
            }
            __syncthreads();

            // ---- scores: rows {2ty+i} x cols {2tx+jj}; logical col j read
            //      at physical j^swk (K) / j^swq (Q) ----
            float s00 = 0.f, s01 = 0.f, s10 = 0.f, s11 = 0.f;
            const int r0 = tx*2, r1 = r0 + 1;
            #pragma unroll
            for (int j = 0; j < 32; ++j) {
                const int jk = (j ^ swk) << 2;
                const int jq = (j ^ swq) << 2;
                float4 k0 = *(const float4*)&Ks[r0][jk];
                float4 k1 = *(const float4*)&Ks[r1][jk];
                float4 q0 = *(const float4*)&Qs[ty*2][jq];
                float4 q1 = *(const float4*)&Qs[ty*2 + 1][jq];
                s00 = fmaf(q0.x,k0.x,s00); s00 = fmaf(q0.y,k0.y,s00);
                s00 = fmaf(q0.z,k0.z,s00); s00 = fmaf(q0.w,k0.w,s00);
                s01 = fmaf(q0.x,k1.x,s01); s01 = fmaf(q0.y,k1.y,s01);
                s01 = fmaf(q0.z,k1.z,s01); s01 = fmaf(q0.w,k1.w,s01);
                s10 = fmaf(q1.x,k0.x,s10); s10 = fmaf(q1.y,k0.y,s10);
                s10 = fmaf(q1.z,k0.z,s10); s10 = fmaf(q1.w,k0.w,s10);
                s11 = fmaf(q1.x,k1.x,s11); s11 = fmaf(q1.y,k1.y,s11);
                s11 = fmaf(q1.z,k1.z,s11); s11 = fmaf(q1.w,k1.w,s11);
            }
            float sc[2][2] = {{s00, s01}, {s10, s11}};

            // ---- online softmax (row spread over 16 tx lanes) ----
            const int qg0 = qt*64 + ty*2;
            const int kg0 = kt*32 + tx*2;
            #pragma unroll
            for (int i = 0; i < 2; ++i) {
                const int qg = qg0 + i;
                if (kg0     > qg) sc[i][0] = -INFINITY;
                if (kg0 + 1 > qg) sc[i][1] = -INFINITY;
                float mx = fmaxf(sc[i][0], sc[i][1]);
                #pragma unroll
                for (int off = 1; off < 16; off <<= 1) mx = fmaxf(mx, __shfl_xor(mx, off));
                const float mnew = fmaxf(m_i[i], mx);
                const float alpha = __expf(m_i[i] - mnew);   // 0 on first tile
                const float p0 = __expf(sc[i][0] - mnew);
                const float p1 = __expf(sc[i][1] - mnew);
                float rs = p0 + p1;
                #pragma unroll
                for (int off = 1; off < 16; off <<= 1) rs += __shfl_xor(rs, off);
                l_i[i] = l_i[i]*alpha + rs;
                m_i[i] = mnew;
                #pragma unroll
                for (int d = 0; d < 8; ++d) O[i][d] *= alpha;
                *(float2*)&Ps[ty*2 + i][tx*2] = make_float2(p0, p1);
            }
            __syncthreads();

            // ---- PV: O[i][·] += P[row][kc] * V[kc][{d0, 64+d0}] ----
            #pragma unroll 4
            for (int kc = 0; kc < 32; ++kc) {
                float4 v0 = *(const float4*)&Vs[kc][d0];
                float4 v1 = *(const float4*)&Vs[kc][64 + d0];
                #pragma unroll
                for (int i = 0; i < 2; ++i) {
                    const float p = Ps[ty*2 + i][kc];
                    O[i][0] = fmaf(p, v0.x, O[i][0]);
                    O[i][1] = fmaf(p, v0.y, O[i][1]);
                    O[i][2] = fmaf(p, v0.z, O[i][2]);
                    O[i][3] = fmaf(p, v0.w, O[i][3]);
                    O[i][4] = fmaf(p, v1.x, O[i][4]);
                    O[i][5] = fmaf(p, v1.y, O[i][5]);
                    O[i][6] = fmaf(p, v1.z, O[i][6]);
                    O[i][7] = fmaf(p, v1.w, O[i][7]);
                }
            }
            // next iteration's first __syncthreads orders Vs/Ps overwrite
        }

        // ---- epilogue: normalize, store Y rows of THIS q-tile ----
        // Y aliases Q: this block's phase-qt Q rows were consumed into LDS.
        #pragma unroll
        for (int i = 0; i < 2; ++i) {
            const float inv = 1.0f / l_i[i];
            const size_t row = (size_t)(b*SEQ + qt*64 + ty*2 + i);
            float4 o0 = make_float4(O[i][0]*inv, O[i][1]*inv, O[i][2]*inv, O[i][3]*inv);
            float4 o1 = make_float4(O[i][4]*inv, O[i][5]*inv, O[i][6]*inv, O[i][7]*inv);
            *(float4*)&Y[row * DIM + headoff + d0]      = o0;
            *(float4*)&Y[row * DIM + headoff + 64 + d0] = o1;
        }
    }
}

// ---------------------------------------------------------------------------
extern "C" void kernel_launch(void* const* d_in, const int* in_sizes, int n_in,
                              void* d_out, int out_size, void* d_ws, size_t ws_size,
                              hipStream_t stream)
{
    const float* x  = (const float*)d_in[0];
    const float* Wq = (const float*)d_in[1];
    const float* Wk = (const float*)d_in[2];
    const float* Wv = (const float*)d_in[3];
    const float* Wo = (const float*)d_in[4];
    float* out = (float*)d_out;

    // Workspace: 3 buffers of 32 MB (Q, K, V). Attention output Y aliases Q.
    float* Qb = (float*)d_ws;
    float* Kb = Qb + (size_t)MTOT * DIM;
    float* Vb = Kb + (size_t)MTOT * DIM;
    float* Yb = Qb;

    gemm_nt_f32<<<dim3(DIM/128, MTOT/128, 3), dim3(256), 0, stream>>>(
        x, Wq, Wk, Wv, Qb, Kb, Vb, MTOT, DIM, DIM);
    rmsnorm_rope<<<dim3(MTOT/4, NHEADS, 2), dim3(256), 0, stream>>>(Qb, Kb);
    attn_f32<<<dim3(SEQ/128, NHEADS, BATCH), dim3(512), 0, stream>>>(Qb, Kb, Vb, Yb);
    gemm_nt_f32<<<dim3(DIM/128, MTOT/128, 1), dim3(256), 0, stream>>>(
        Yb, Wo, Wo, Wo, out, out, out, MTOT, DIM, DIM);
}

// Round 6
// 1471.755 us; speedup vs baseline: 3.8140x; 1.7764x over previous
//
#include <hip/hip_runtime.h>
#include <hip/hip_bf16.h>
#include <cmath>

#define DIM 2048
#define NHEADS 16
#define HDIM 128
#define SEQ 2048
#define BATCH 2
#define MTOT (BATCH*SEQ)
#define RMS_EPS 1.1920928955078125e-07f

typedef float  f32x16 __attribute__((ext_vector_type(16)));
typedef short  bf16x8 __attribute__((ext_vector_type(8)));

#define AS1 __attribute__((address_space(1)))
#define AS3 __attribute__((address_space(3)))

// ---------------------------------------------------------------------------
// fp32 -> (hi, lo) bf16 split, RNE both halves. x ~= hi + lo, |err| ~ 2^-18|x|
// ---------------------------------------------------------------------------
__device__ __forceinline__ void split1(float x, unsigned short& h, unsigned short& l)
{
    unsigned int xb = __float_as_uint(x);
    unsigned int hb = (xb + 0x7FFFu + ((xb >> 16) & 1u)) & 0xFFFF0000u;
    float hf = __uint_as_float(hb);
    h = (unsigned short)(hb >> 16);
    float r = x - hf;                      // exact in fp32
    unsigned int rb = __float_as_uint(r);
    l = (unsigned short)((rb + 0x7FFFu + ((rb >> 16) & 1u)) >> 16);
}

// Split up to 4 equal-size fp32 matrices (selected by blockIdx.z) into
// contiguous hi/lo bf16 arrays. n4 = elements/4 per matrix.
__global__ __launch_bounds__(256) void split4(
    const float* __restrict__ a, const float* __restrict__ b,
    const float* __restrict__ c, const float* __restrict__ d,
    unsigned short* __restrict__ hi, unsigned short* __restrict__ lo, int n4)
{
    const float* src = (blockIdx.z == 0) ? a : (blockIdx.z == 1) ? b
                     : (blockIdx.z == 2) ? c : d;
    unsigned short* H = hi + (size_t)blockIdx.z * n4 * 4;
    unsigned short* L = lo + (size_t)blockIdx.z * n4 * 4;
    for (int i = blockIdx.x*256 + threadIdx.x; i < n4; i += gridDim.x*256) {
        float4 v = ((const float4*)src)[i];
        ushort4 hv, lv;
        split1(v.x, hv.x, lv.x);
        split1(v.y, hv.y, lv.y);
        split1(v.z, hv.z, lv.z);
        split1(v.w, hv.w, lv.w);
        ((ushort4*)H)[i] = hv;
        ((ushort4*)L)[i] = lv;
    }
}

// ---------------------------------------------------------------------------
// Split-bf16 MFMA GEMM (NT): C[M,N] = A[M,K] @ B[N,K]^T in ~fp32 precision via
// C = Ah@Bh + Ah@Bl + Al@Bh  (mfma_f32_32x32x16_bf16, fp32 accumulate).
// 128x128 tile, BK=64, 256 thr = 4 waves (2x2), wave tile 64x64 = 2x2 frags.
// LDS: 4 tiles (Ah,Al,Bh,Bl) of 128x64 bf16 = 64 KB -> 2 blocks/CU.
// Staging: global_load_lds width=16, linear LDS dest (slot = row*8 + kcp),
//   kcp = kc ^ (row&7) paid on the (permuted) GLOBAL source, and again on the
//   fragment READ (both-sides swizzle) -> frag ds_read_b128 ~conflict-free.
// Weight matrix selected by blockIdx.z (offset z*N*K into Wh/Wl).
// ---------------------------------------------------------------------------
__global__ __launch_bounds__(256, 2) void gemm_nt_bf16x2(
    const unsigned short* __restrict__ Ah, const unsigned short* __restrict__ Al,
    const unsigned short* __restrict__ Wh, const unsigned short* __restrict__ Wl,
    float* __restrict__ C0, float* __restrict__ C1, float* __restrict__ C2,
    int N, int K)
{
    const unsigned short* Bh = Wh + (size_t)blockIdx.z * N * K;
    const unsigned short* Bl = Wl + (size_t)blockIdx.z * N * K;
    float* C = (blockIdx.z == 0) ? C0 : (blockIdx.z == 1) ? C1 : C2;

    __shared__ short smem[4 * 8192];   // Ah | Al | Bh | Bl, 16 KB each

    const int tid  = threadIdx.x;
    const int lane = tid & 63;
    const int wid  = tid >> 6;
    const int wr   = wid >> 1, wc = wid & 1;
    const int m0 = blockIdx.y * 128, n0 = blockIdx.x * 128;

    // staging map: slot s in [0,1024): row = s>>3, kcp = s&7, kcl = kcp^(row&7)
    int soff[4];
    #pragma unroll
    for (int q = 0; q < 4; ++q) {
        int s = tid + q*256;
        int row = s >> 3, kcp = s & 7;
        int kcl = kcp ^ (row & 7);
        soff[q] = row * K + kcl * 8;     // element offset within panel
    }
    const unsigned short* gAh = Ah + (size_t)m0 * K;
    const unsigned short* gAl = Al + (size_t)m0 * K;
    const unsigned short* gBh = Bh + (size_t)n0 * K;
    const unsigned short* gBl = Bl + (size_t)n0 * K;

    f32x16 acc[2][2];
    #pragma unroll
    for (int mi = 0; mi < 2; ++mi)
        #pragma unroll
        for (int ni = 0; ni < 2; ++ni)
            #pragma unroll
            for (int r = 0; r < 16; ++r) acc[mi][ni][r] = 0.0f;

    const int l31 = lane & 31, hi5 = lane >> 5, l7 = lane & 7;
    // LDS short-index bases for fragment rows (row*64 shorts = 128B rows)
    const int a0 = (wr*64 +  0 + l31) * 64;
    const int a1 = (wr*64 + 32 + l31) * 64;
    const int b0 = (wc*64 +  0 + l31) * 64;
    const int b1 = (wc*64 + 32 + l31) * 64;

    for (int kt = 0; kt < K; kt += 64) {
        // ---- stage 4 tiles via global_load_lds (16B per lane per call) ----
        #pragma unroll
        for (int q = 0; q < 4; ++q) {
            int s = tid + q*256;
            __builtin_amdgcn_global_load_lds((const AS1 void*)(gAh + soff[q] + kt),
                (AS3 void*)((AS3 short*)smem + s*8), 16, 0, 0);
        }
        #pragma unroll
        for (int q = 0; q < 4; ++q) {
            int s = tid + q*256;
            __builtin_amdgcn_global_load_lds((const AS1 void*)(gAl + soff[q] + kt),
                (AS3 void*)((AS3 short*)smem + 8192 + s*8), 16, 0, 0);
        }
        #pragma unroll
        for (int q = 0; q < 4; ++q) {
            int s = tid + q*256;
            __builtin_amdgcn_global_load_lds((const AS1 void*)(gBh + soff[q] + kt),
                (AS3 void*)((AS3 short*)smem + 16384 + s*8), 16, 0, 0);
        }
        #pragma unroll
        for (int q = 0; q < 4; ++q) {
            int s = tid + q*256;
            __builtin_amdgcn_global_load_lds((const AS1 void*)(gBl + soff[q] + kt),
                (AS3 void*)((AS3 short*)smem + 24576 + s*8), 16, 0, 0);
        }
        __syncthreads();   // drains vmcnt, then barrier: tiles ready

        // ---- compute: 4 k-slices of 16; frag k-chunk kcp = (ks*2+hi5)^l7 ----
        #pragma unroll
        for (int ks = 0; ks < 4; ++ks) {
            const int kcp = ((ks*2 + hi5) ^ l7) * 8;
            bf16x8 ah0 = *(const bf16x8*)&smem[a0 + kcp];
            bf16x8 ah1 = *(const bf16x8*)&smem[a1 + kcp];
            bf16x8 al0 = *(const bf16x8*)&smem[ 8192 + a0 + kcp];
            bf16x8 al1 = *(const bf16x8*)&smem[ 8192 + a1 + kcp];
            bf16x8 bh0 = *(const bf16x8*)&smem[16384 + b0 + kcp];
            bf16x8 bh1 = *(const bf16x8*)&smem[16384 + b1 + kcp];
            bf16x8 bl0 = *(const bf16x8*)&smem[24576 + b0 + kcp];
            bf16x8 bl1 = *(const bf16x8*)&smem[24576 + b1 + kcp];

            acc[0][0] = __builtin_amdgcn_mfma_f32_32x32x16_bf16(ah0, bh0, acc[0][0], 0,0,0);
            acc[0][1] = __builtin_amdgcn_mfma_f32_32x32x16_bf16(ah0, bh1, acc[0][1], 0,0,0);
            acc[1][0] = __builtin_amdgcn_mfma_f32_32x32x16_bf16(ah1, bh0, acc[1][0], 0,0,0);
            acc[1][1] = __builtin_amdgcn_mfma_f32_32x32x16_bf16(ah1, bh1, acc[1][1], 0,0,0);
            acc[0][0] = __builtin_amdgcn_mfma_f32_32x32x16_bf16(ah0, bl0, acc[0][0], 0,0,0);
            acc[0][1] = __builtin_amdgcn_mfma_f32_32x32x16_bf16(ah0, bl1, acc[0][1], 0,0,0);
            acc[1][0] = __builtin_amdgcn_mfma_f32_32x32x16_bf16(ah1, bl0, acc[1][0], 0,0,0);
            acc[1][1] = __builtin_amdgcn_mfma_f32_32x32x16_bf16(ah1, bl1, acc[1][1], 0,0,0);
            acc[0][0] = __builtin_amdgcn_mfma_f32_32x32x16_bf16(al0, bh0, acc[0][0], 0,0,0);
            acc[0][1] = __builtin_amdgcn_mfma_f32_32x32x16_bf16(al0, bh1, acc[0][1], 0,0,0);
            acc[1][0] = __builtin_amdgcn_mfma_f32_32x32x16_bf16(al1, bh0, acc[1][0], 0,0,0);
            acc[1][1] = __builtin_amdgcn_mfma_f32_32x32x16_bf16(al1, bh1, acc[1][1], 0,0,0);
        }
        __syncthreads();   // all frag reads done before next stage overwrites
    }

    // ---- epilogue: C/D layout col=lane&31, row=(r&3)+8*(r>>2)+4*(lane>>5) ----
    #pragma unroll
    for (int mi = 0; mi < 2; ++mi)
        #pragma unroll
        for (int ni = 0; ni < 2; ++ni) {
            const int gcol = n0 + wc*64 + ni*32 + l31;
            #pragma unroll
            for (int r = 0; r < 16; ++r) {
                const int grow = m0 + wr*64 + mi*32 + (r & 3) + 8*(r >> 2) + 4*hi5;
                C[(size_t)grow * N + gcol] = acc[mi][ni][r];
            }
        }
}

// ---------------------------------------------------------------------------
// Fused RMSNorm (per head, over 128) + RoPE (half-split rotary). Unchanged.
// ---------------------------------------------------------------------------
__global__ __launch_bounds__(256) void rmsnorm_rope(float* __restrict__ Q,
                                                    float* __restrict__ Kp)
{
    const int wave = threadIdx.x >> 6;
    const int lane = threadIdx.x & 63;
    const int m = blockIdx.x * 4 + wave;
    const int h = blockIdx.y;
    float* T = blockIdx.z ? Kp : Q;
    const int s = m & (SEQ - 1);

    float* row = T + (size_t)m * DIM + h * HDIM;
    float x1 = row[lane];
    float x2 = row[lane + 64];

    float ss = x1*x1 + x2*x2;
    #pragma unroll
    for (int off = 32; off > 0; off >>= 1) ss += __shfl_xor(ss, off);
    const float r = rsqrtf(ss * (1.0f/128.0f) + RMS_EPS);
    x1 *= r; x2 *= r;

    const float e = (float)lane * (1.0f/64.0f);
    const float inv_freq = 1.0f / powf(10000.0f, e);
    const float fr = (float)s * inv_freq;
    const float c = cosf(fr), sn = sinf(fr);

    row[lane]      =  x1 * c + x2 * sn;
    row[lane + 64] = -x1 * sn + x2 * c;
}

// ---------------------------------------------------------------------------
// Flash-style causal attention, fp32 — R5 version (read-side XOR), unchanged.
// ---------------------------------------------------------------------------
__global__ __launch_bounds__(512, 4) void attn_f32(
    const float* __restrict__ Q, const float* __restrict__ Kp,
    const float* __restrict__ V, float* __restrict__ Y)
{
    const int qpair = blockIdx.x;
    const int h = blockIdx.y, b = blockIdx.z;
    const int tid = threadIdx.x;
    const int ty = tid >> 4;
    const int tx = tid & 15;

    __shared__ float Qs[64][HDIM];
    __shared__ float Ks[32][HDIM];
    __shared__ float Vs[32][HDIM];
    __shared__ float Ps[64][35];

    const size_t headoff = (size_t)h * HDIM;
    const float* Kbase = Kp + ((size_t)(b*SEQ)) * DIM + headoff;
    const float* Vbase = V  + ((size_t)(b*SEQ)) * DIM + headoff;
    const float scale = 0.08838834764831845f;

    const int swk = tx & 7;
    const int swq = ty & 7;
    const int d0  = tx * 4;

    for (int phase = 0; phase < 2; ++phase) {
        const int qt = phase ? (SEQ/64 - 1 - qpair) : qpair;
        const float* Qbase = Q + ((size_t)(b*SEQ + qt*64)) * DIM + headoff;

        #pragma unroll
        for (int i = 0; i < 4; ++i) {
            int f = tid + i*512;
            int row = f >> 5, c4 = f & 31;
            float4 qv = *(const float4*)&Qbase[(size_t)row * DIM + (c4 << 2)];
            qv.x *= scale; qv.y *= scale; qv.z *= scale; qv.w *= scale;
            int c4s = c4 ^ ((row >> 1) & 7);
            *(float4*)&Qs[row][c4s << 2] = qv;
        }

        float m_i[2] = {-INFINITY, -INFINITY};
        float l_i[2] = {0.0f, 0.0f};
        float O[2][8] = {};

        const int ntiles = 2*qt + 2;
        for (int kt = 0; kt < ntiles; ++kt) {
            float4 kreg[2], vreg[2];
            int rrow[2], rc4[2];
            #pragma unroll
            for (int i = 0; i < 2; ++i) {
                int f = tid + i*512;
                rrow[i] = f >> 5; rc4[i] = f & 31;
                size_t g = (size_t)(kt*32 + rrow[i]) * DIM + (rc4[i] << 2);
                kreg[i] = *(const float4*)&Kbase[g];
                vreg[i] = *(const float4*)&Vbase[g];
            }
            __syncthreads();
            #pragma unroll
            for (int i = 0; i < 2; ++i) {
                int c4s = rc4[i] ^ ((rrow[i] >> 1) & 7);
                *(float4*)&Ks[rrow[i]][c4s << 2] = kreg[i];
                *(float4*)&Vs[rrow[i]][rc4[i] << 2] = vreg[i];
            }
            __syncthreads();

            float s00 = 0.f, s01 = 0.f, s10 = 0.f, s11 = 0.f;
            const int r0 = tx*2, r1 = r0 + 1;
            #pragma unroll
            for (int j = 0; j < 32; ++j) {
                const int jk = (j ^ swk) << 2;
                const int jq = (j ^ swq) << 2;
                float4 k0 = *(const float4*)&Ks[r0][jk];
                float4 k1 = *(const float4*)&Ks[r1][jk];
                float4 q0 = *(const float4*)&Qs[ty*2][jq];
                float4 q1 = *(const float4*)&Qs[ty*2 + 1][jq];
                s00 = fmaf(q0.x,k0.x,s00); s00 = fmaf(q0.y,k0.y,s00);
                s00 = fmaf(q0.z,k0.z,s00); s00 = fmaf(q0.w,k0.w,s00);
                s01 = fmaf(q0.x,k1.x,s01); s01 = fmaf(q0.y,k1.y,s01);
                s01 = fmaf(q0.z,k1.z,s01); s01 = fmaf(q0.w,k1.w,s01);
                s10 = fmaf(q1.x,k0.x,s10); s10 = fmaf(q1.y,k0.y,s10);
                s10 = fmaf(q1.z,k0.z,s10); s10 = fmaf(q1.w,k0.w,s10);
                s11 = fmaf(q1.x,k1.x,s11); s11 = fmaf(q1.y,k1.y,s11);
                s11 = fmaf(q1.z,k1.z,s11); s11 = fmaf(q1.w,k1.w,s11);
            }
            float sc[2][2] = {{s00, s01}, {s10, s11}};

            const int qg0 = qt*64 + ty*2;
            const int kg0 = kt*32 + tx*2;
            #pragma unroll
            for (int i = 0; i < 2; ++i) {
                const int qg = qg0 + i;
                if (kg0     > qg) sc[i][0] = -INFINITY;
                if (kg0 + 1 > qg) sc[i][1] = -INFINITY;
                float mx = fmaxf(sc[i][0], sc[i][1]);
                #pragma unroll
                for (int off = 1; off < 16; off <<= 1) mx = fmaxf(mx, __shfl_xor(mx, off));
                const float mnew = fmaxf(m_i[i], mx);
                const float alpha = __expf(m_i[i] - mnew);
                const float p0 = __expf(sc[i][0] - mnew);
                const float p1 = __expf(sc[i][1] - mnew);
                float rs = p0 + p1;
                #pragma unroll
                for (int off = 1; off < 16; off <<= 1) rs += __shfl_xor(rs, off);
                l_i[i] = l_i[i]*alpha + rs;
                m_i[i] = mnew;
                #pragma unroll
                for (int d = 0; d < 8; ++d) O[i][d] *= alpha;
                *(float2*)&Ps[ty*2 + i][tx*2] = make_float2(p0, p1);
            }
            __syncthreads();

            #pragma unroll 4
            for (int kc = 0; kc < 32; ++kc) {
                float4 v0 = *(const float4*)&Vs[kc][d0];
                float4 v1 = *(const float4*)&Vs[kc][64 + d0];
                #pragma unroll
                for (int i = 0; i < 2; ++i) {
                    const float p = Ps[ty*2 + i][kc];
                    O[i][0] = fmaf(p, v0.x, O[i][0]);
                    O[i][1] = fmaf(p, v0.y, O[i][1]);
                    O[i][2] = fmaf(p, v0.z, O[i][2]);
                    O[i][3] = fmaf(p, v0.w, O[i][3]);
                    O[i][4] = fmaf(p, v1.x, O[i][4]);
                    O[i][5] = fmaf(p, v1.y, O[i][5]);
                    O[i][6] = fmaf(p, v1.z, O[i][6]);
                    O[i][7] = fmaf(p, v1.w, O[i][7]);
                }
            }
        }

        #pragma unroll
        for (int i = 0; i < 2; ++i) {
            const float inv = 1.0f / l_i[i];
            const size_t row = (size_t)(b*SEQ + qt*64 + ty*2 + i);
            float4 o0 = make_float4(O[i][0]*inv, O[i][1]*inv, O[i][2]*inv, O[i][3]*inv);
            float4 o1 = make_float4(O[i][4]*inv, O[i][5]*inv, O[i][6]*inv, O[i][7]*inv);
            *(float4*)&Y[row * DIM + headoff + d0]      = o0;
            *(float4*)&Y[row * DIM + headoff + 64 + d0] = o1;
        }
    }
}

// ---------------------------------------------------------------------------
extern "C" void kernel_launch(void* const* d_in, const int* in_sizes, int n_in,
                              void* d_out, int out_size, void* d_ws, size_t ws_size,
                              hipStream_t stream)
{
    const float* x  = (const float*)d_in[0];
    const float* Wq = (const float*)d_in[1];
    const float* Wk = (const float*)d_in[2];
    const float* Wv = (const float*)d_in[3];
    const float* Wo = (const float*)d_in[4];
    float* out = (float*)d_out;

    // Workspace layout (192 MB total):
    //   Qb, Kb, Vb: fp32 32 MB each (Y aliases Qb)
    //   xh, xl:     bf16 16 MB each (reused as Yh/Yl after attention)
    //   WhAll,WlAll:bf16 [Wq;Wk;Wv;Wo] 32 MB each
    float* Qb = (float*)d_ws;
    float* Kb = Qb + (size_t)MTOT * DIM;
    float* Vb = Kb + (size_t)MTOT * DIM;
    unsigned short* xh    = (unsigned short*)(Vb + (size_t)MTOT * DIM);
    unsigned short* xl    = xh + (size_t)MTOT * DIM;
    unsigned short* WhAll = xl + (size_t)MTOT * DIM;
    unsigned short* WlAll = WhAll + (size_t)4 * DIM * DIM;
    float* Yb = Qb;

    // 1) split x and the four weight matrices into bf16 hi/lo
    split4<<<dim3(2048, 1, 1), dim3(256), 0, stream>>>(
        x, x, x, x, xh, xl, MTOT*DIM/4);
    split4<<<dim3(2048, 1, 4), dim3(256), 0, stream>>>(
        Wq, Wk, Wv, Wo, WhAll, WlAll, DIM*DIM/4);

    // 2) QKV projections via split-bf16 MFMA (z selects Wq/Wk/Wv and Q/K/V)
    gemm_nt_bf16x2<<<dim3(DIM/128, MTOT/128, 3), dim3(256), 0, stream>>>(
        xh, xl, WhAll, WlAll, Qb, Kb, Vb, DIM, DIM);

    // 3) fused RMSNorm + RoPE on Q and K
    rmsnorm_rope<<<dim3(MTOT/4, NHEADS, 2), dim3(256), 0, stream>>>(Qb, Kb);

    // 4) causal flash attention (Y aliases Q)
    attn_f32<<<dim3(SEQ/128, NHEADS, BATCH), dim3(512), 0, stream>>>(Qb, Kb, Vb, Yb);

    // 5) split Y (reuse xh/xl), then output projection with Wo (4th panel)
    split4<<<dim3(2048, 1, 1), dim3(256), 0, stream>>>(
        Yb, Yb, Yb, Yb, xh, xl, MTOT*DIM/4);
    gemm_nt_bf16x2<<<dim3(DIM/128, MTOT/128, 1), dim3(256), 0, stream>>>(
        xh, xl, WhAll + (size_t)3*DIM*DIM, WlAll + (size_t)3*DIM*DIM,
        out, out, out, DIM, DIM);
}